// Round 1
// baseline (311.383 us; speedup 1.0000x reference)
//
#include <hip/hip_runtime.h>

#define D 64

// Monotonic float->uint encoding: preserves ordering under unsigned max.
__device__ __forceinline__ unsigned int enc_f32(float f) {
    unsigned int u = __float_as_uint(f);
    return (u & 0x80000000u) ? ~u : (u | 0x80000000u);
}
__device__ __forceinline__ float dec_f32(unsigned int u) {
    unsigned int b = (u & 0x80000000u) ? (u ^ 0x80000000u) : ~u;
    return __uint_as_float(b);
}

// One wave per edge; lane j handles feature j.
__global__ __launch_bounds__(256) void scatter_max_kernel(
    const float* __restrict__ h, const int* __restrict__ src,
    const int* __restrict__ dst, unsigned int* __restrict__ enc, int n_edges)
{
    int gid = blockIdx.x * 256 + threadIdx.x;
    int e = gid >> 6;
    if (e >= n_edges) return;
    int j = gid & 63;
    int s = src[e];
    int d = dst[e];
    float v = h[s * D + j];
    atomicMax(&enc[d * D + j], enc_f32(v));
}

// Decode h_N tile + GEMM (out = h_N @ W^T + b), 64 nodes per block.
__global__ __launch_bounds__(256) void finalize_kernel(
    const unsigned int* __restrict__ enc, const float* __restrict__ W,
    const float* __restrict__ bvec, float* __restrict__ out, int n_nodes)
{
    __shared__ float Ht[64][65];   // decoded h_N tile (padded: no bank conflict)
    __shared__ float Wt[64][65];   // Wt[k][j] = W[j][k]
    __shared__ float bs[64];
    int t = threadIdx.x;
    int node0 = blockIdx.x * 64;
    int nrem = n_nodes - node0;    // valid rows in this tile (<=64)

    for (int i = t; i < 4096; i += 256) {
        int j = i >> 6, k = i & 63;
        Wt[k][j] = W[i];           // coalesced read of W row-major
    }
    if (t < 64) bs[t] = bvec[t];
    for (int i = t; i < 4096; i += 256) {
        int r = i >> 6, k = i & 63;
        float v = 0.0f;
        if (r < nrem) {
            unsigned int u = enc[(node0 + r) * D + k];
            v = (u == 0u) ? 0.0f : dec_f32(u);
        }
        Ht[r][k] = v;
    }
    __syncthreads();

    int c = t & 63;          // output feature (lane)
    int r0 = t >> 6;         // wave id 0..3 -> rows r0*16 .. r0*16+15
    float wcol[64];
    #pragma unroll
    for (int k = 0; k < 64; ++k) wcol[k] = Wt[k][c];   // hoist W column to VGPRs
    float bc = bs[c];

    for (int p = 0; p < 16; ++p) {
        int r = r0 * 16 + p;
        if (r >= nrem) break;
        float acc = bc;
        #pragma unroll
        for (int k = 0; k < 64; ++k)
            acc += Ht[r][k] * wcol[k];   // Ht: wave-broadcast (free); wcol: VGPR
        out[(node0 + r) * D + c] = acc;
    }
}

// out[idx[i], :] = h[idx[i], :]
__global__ __launch_bounds__(256) void overwrite_kernel(
    const float* __restrict__ h, const int* __restrict__ idx,
    float* __restrict__ out, int n_idx)
{
    int gid = blockIdx.x * 256 + threadIdx.x;
    int i = gid >> 6;
    if (i >= n_idx) return;
    int j = gid & 63;
    int node = idx[i];
    out[node * D + j] = h[node * D + j];
}

extern "C" void kernel_launch(void* const* d_in, const int* in_sizes, int n_in,
                              void* d_out, int out_size, void* d_ws, size_t ws_size,
                              hipStream_t stream)
{
    const float* h   = (const float*)d_in[0];
    const float* W   = (const float*)d_in[1];
    const float* b   = (const float*)d_in[2];
    const int*   src = (const int*)d_in[3];
    const int*   dst = (const int*)d_in[4];
    const int*   idx = (const int*)d_in[5];
    float* out = (float*)d_out;

    int n_nodes = in_sizes[0] / D;
    int n_edges = in_sizes[3];
    int n_idx   = in_sizes[5];

    unsigned int* enc = (unsigned int*)d_ws;

    // Sentinel-init the segment-max buffer (required every call: ws not re-poisoned).
    hipMemsetAsync(enc, 0, (size_t)n_nodes * D * sizeof(unsigned int), stream);

    {
        int total = n_edges * D;   // 76.8M threads, one wave per edge
        scatter_max_kernel<<<(total + 255) / 256, 256, 0, stream>>>(h, src, dst, enc, n_edges);
    }
    finalize_kernel<<<(n_nodes + 63) / 64, 256, 0, stream>>>(enc, W, b, out, n_nodes);
    {
        int total = n_idx * D;
        overwrite_kernel<<<(total + 255) / 256, 256, 0, stream>>>(h, idx, out, n_idx);
    }
}